// Round 8
// baseline (664.462 us; speedup 1.0000x reference)
//
#include <hip/hip_runtime.h>
#include <stdint.h>

#define N_ROWS 65536
#define DIM 1024
#define HID 128
#define FD 512
#define KCB 1024
#define HALFCNT 33554432u

#define OFF_Q    1
#define OFF_PERP 33554433
#define OFF_ENC  33554434
#define OFF_ND   100663298

typedef __attribute__((ext_vector_type(8))) short sh8;     // 8 bf16 in 4 VGPRs
typedef __attribute__((ext_vector_type(4))) float f32x4;

__device__ __forceinline__ uint32_t rotl32(uint32_t v, int r) { return (v << r) | (v >> (32 - r)); }

// JAX threefry2x32 with key (0, 42)
__device__ __forceinline__ void threefry(uint32_t c0, uint32_t c1, uint32_t& o0, uint32_t& o1) {
    const uint32_t ks0 = 0u, ks1 = 42u, ks2 = 0x1BD11BDAu ^ 0u ^ 42u;
    uint32_t x0 = c0 + ks0, x1 = c1 + ks1;
#define TFR(r) x0 += x1; x1 = rotl32(x1, r); x1 ^= x0;
    TFR(13) TFR(15) TFR(26) TFR(6)  x0 += ks1; x1 += ks2 + 1u;
    TFR(17) TFR(29) TFR(16) TFR(24) x0 += ks2; x1 += ks0 + 2u;
    TFR(13) TFR(15) TFR(26) TFR(6)  x0 += ks0; x1 += ks1 + 3u;
    TFR(17) TFR(29) TFR(16) TFR(24) x0 += ks1; x1 += ks2 + 4u;
    TFR(13) TFR(15) TFR(26) TFR(6)  x0 += ks2; x1 += ks0 + 5u;
#undef TFR
    o0 = x0; o1 = x1;
}

// gumbel via hw v_log_f32 (same bits as rounds 6/7)
__device__ __forceinline__ float gumbel_f32(uint32_t b) {
    uint32_t m = b >> 9;
    float u = m ? (float)m * 1.1920928955078125e-07f : 1.17549435e-38f;
    const float LN2 = 0.6931471805599453f;
    return -LN2 * __log2f(-LN2 * __log2f(u));
}

__device__ __forceinline__ ushort bf16rne(float f) {
    uint32_t u = __float_as_uint(f);
    return (ushort)((u + 0x7FFFu + ((u >> 16) & 1u)) >> 16);
}
__device__ __forceinline__ uint32_t pack2rne(float a, float b) {
    return (uint32_t)bf16rne(a) | ((uint32_t)bf16rne(b) << 16);
}

// async global->LDS, 16B per lane
__device__ __forceinline__ void async_cp16(const void* g, void* l) {
    __builtin_amdgcn_global_load_lds(
        (const __attribute__((address_space(1))) void*)g,
        (__attribute__((address_space(3))) void*)l, 16, 0, 0);
}

// Fused prep: [0,256) codebook bf16+f64 norms; [256,384) W1T; [384,640) W2T; [640] zero.
__global__ __launch_bounds__(256) void k_prep(const float* __restrict__ cb, const float* __restrict__ W1,
                                              const float* __restrict__ W2,
                                              ushort* __restrict__ cbh, double* __restrict__ cc,
                                              ushort* __restrict__ w1th, ushort* __restrict__ w2th,
                                              int* __restrict__ counts, double* __restrict__ lossb) {
    int gb = blockIdx.x, t = threadIdx.x;
    if (gb < 256) {
        int k = gb * 4 + (t >> 6), l = t & 63;
        const float4* row = (const float4*)(cb + (size_t)k * FD);
        float4 a = row[l * 2], b = row[l * 2 + 1];
        float v[8] = {a.x, a.y, a.z, a.w, b.x, b.y, b.z, b.w};
        double s = 0.0;
        uint32_t hu[4];
        #pragma unroll
        for (int e = 0; e < 4; ++e) {
            hu[e] = pack2rne(v[2 * e], v[2 * e + 1]);
            s = fma((double)v[2 * e], (double)v[2 * e], s);
            s = fma((double)v[2 * e + 1], (double)v[2 * e + 1], s);
        }
        *(uint4*)(cbh + (size_t)k * FD + l * 8) = make_uint4(hu[0], hu[1], hu[2], hu[3]);
        for (int off = 32; off; off >>= 1) s += __shfl_down(s, off, 64);
        if (l == 0) cc[k] = s;
    } else if (gb < 384) {
        int c = gb - 256;
        #pragma unroll
        for (int u = 0; u < 4; ++u) {
            int k = t + u * 256;
            w1th[(size_t)c * DIM + k] = bf16rne(W1[(size_t)k * HID + c]);
        }
    } else if (gb < 640) {
        int c = (gb - 384) * 2 + (t >> 7);
        int tt = t & 127;
        w2th[(size_t)c * HID + tt] = bf16rne(W2[(size_t)tt * FD + c]);
    } else {
        for (int k = t; k < KCB; k += 256) counts[k] = 0;
        lossb[t] = 0.0;
    }
}

// Fused MLP, 64 rows/block: phase1 h = relu(X@W1+b1) -> bf16 LDS; phase2 z = h@W2+b2 -> zbh + zz.
// Same MFMA K-order / lane mappings as round 7 => bitwise-identical zbh/zz.
__global__ __launch_bounds__(256) void kAB(const float* __restrict__ X, const ushort* __restrict__ w1th,
                                           const float* __restrict__ b1, const ushort* __restrict__ w2th,
                                           const float* __restrict__ b2,
                                           ushort* __restrict__ zbh, float* __restrict__ zz) {
    __shared__ __align__(16) char lds[24576];   // phase1: x[0,8K) | w1[8K,24K); then h[0,16K)
    __shared__ float zzp[64][2];
    int t = threadIdx.x;
    int lane = t & 63, w = t >> 6;
    int wr = w >> 1, wc = w & 1;
    int lane15 = lane & 15, lg = lane >> 4;
    int n0 = blockIdx.x * 64;
    f32x4 zero4 = {0.f, 0.f, 0.f, 0.f};
    f32x4 acc[2][4];
    #pragma unroll
    for (int i = 0; i < 2; ++i)
        #pragma unroll
        for (int j = 0; j < 4; ++j) acc[i][j] = zero4;

    int xr = t >> 2;                // row this thread converts (64 rows, 4 thr/row)
    int cq = (t & 3) * 2;           // 2 chunks of 8 floats each
    int xsw = xr & 7;

    for (int k0 = 0; k0 < DIM; k0 += 64) {
        #pragma unroll
        for (int i = 0; i < 4; ++i) {          // stage W1T tile: 128 rows x 64k bf16 = 16KB
            int rr = w * 32 + i * 8;
            int row = rr + (lane >> 3);
            int csrc = (lane & 7) ^ (row & 7);
            async_cp16(w1th + (size_t)row * DIM + k0 + csrc * 8, lds + 8192 + rr * 128);
        }
        const float* xp = X + (size_t)(n0 + xr) * DIM + k0 + cq * 8;
        #pragma unroll
        for (int c = 0; c < 2; ++c) {
            float4 a = *(const float4*)(xp + c * 8);
            float4 b = *(const float4*)(xp + c * 8 + 4);
            uint4 hv;
            hv.x = pack2rne(a.x, a.y);
            hv.y = pack2rne(a.z, a.w);
            hv.z = pack2rne(b.x, b.y);
            hv.w = pack2rne(b.z, b.w);
            *(uint4*)(lds + xr * 128 + (((cq + c) ^ xsw) << 4)) = hv;
        }
        __syncthreads();
        #pragma unroll
        for (int kh = 0; kh < 2; ++kh) {
            int ch = kh * 4 + lg;
            sh8 ah[2], bh[4];
            #pragma unroll
            for (int i = 0; i < 2; ++i) {
                int ra = wr * 32 + i * 16 + lane15;
                ah[i] = *(const sh8*)(lds + ra * 128 + ((ch ^ (ra & 7)) << 4));
            }
            #pragma unroll
            for (int j = 0; j < 4; ++j) {
                int rb = wc * 64 + j * 16 + lane15;
                bh[j] = *(const sh8*)(lds + 8192 + rb * 128 + ((ch ^ (rb & 7)) << 4));
            }
            #pragma unroll
            for (int i = 0; i < 2; ++i)
                #pragma unroll
                for (int j = 0; j < 4; ++j)
                    acc[i][j] = __builtin_amdgcn_mfma_f32_16x16x32_bf16(ah[i], bh[j], acc[i][j], 0, 0, 0);
        }
        __syncthreads();
    }
    // phase-1 epilogue: h (bf16) -> LDS [64][128], XOR-swizzled
    #pragma unroll
    for (int j = 0; j < 4; ++j) {
        int hcol = wc * 64 + j * 16 + lane15;
        float b1v = b1[hcol];
        int k8 = hcol >> 3, klo = hcol & 7;
        #pragma unroll
        for (int i = 0; i < 2; ++i)
            #pragma unroll
            for (int r = 0; r < 4; ++r) {
                int row = wr * 32 + i * 16 + lg * 4 + r;
                ushort hb = bf16rne(fmaxf(acc[i][j][r] + b1v, 0.f));
                *(ushort*)(lds + row * 256 + ((k8 ^ (row & 7)) << 4) + klo * 2) = hb;
            }
    }
    __syncthreads();
    // phase 2: z = h @ W2 + b2, 4 chunks of 128 cols; K=128
    float zsum[8];
    #pragma unroll
    for (int e = 0; e < 8; ++e) zsum[e] = 0.f;
    for (int c2 = 0; c2 < 4; ++c2) {
        f32x4 acc2[2][4];
        #pragma unroll
        for (int i = 0; i < 2; ++i)
            #pragma unroll
            for (int j = 0; j < 4; ++j) acc2[i][j] = zero4;
        #pragma unroll
        for (int kh = 0; kh < 4; ++kh) {
            int ch = kh * 4 + lg;
            sh8 ah[2], bh[4];
            #pragma unroll
            for (int i = 0; i < 2; ++i) {
                int ra = wr * 32 + i * 16 + lane15;
                ah[i] = *(const sh8*)(lds + ra * 256 + ((ch ^ (ra & 7)) << 4));
            }
            #pragma unroll
            for (int j = 0; j < 4; ++j) {
                int col = c2 * 128 + wc * 64 + j * 16 + lane15;
                bh[j] = *(const sh8*)(w2th + (size_t)col * HID + ch * 8);
            }
            #pragma unroll
            for (int i = 0; i < 2; ++i)
                #pragma unroll
                for (int j = 0; j < 4; ++j)
                    acc2[i][j] = __builtin_amdgcn_mfma_f32_16x16x32_bf16(ah[i], bh[j], acc2[i][j], 0, 0, 0);
        }
        #pragma unroll
        for (int j = 0; j < 4; ++j) {
            int col = c2 * 128 + wc * 64 + j * 16 + lane15;
            float b2v = b2[col];
            #pragma unroll
            for (int i = 0; i < 2; ++i)
                #pragma unroll
                for (int r = 0; r < 4; ++r) {
                    int row = wr * 32 + i * 16 + lg * 4 + r;
                    float v = acc2[i][j][r] + b2v;
                    zbh[(size_t)(n0 + row) * FD + col] = bf16rne(v);
                    zsum[i * 4 + r] = fmaf(v, v, zsum[i * 4 + r]);
                }
        }
    }
    #pragma unroll
    for (int e = 0; e < 8; ++e) {
        float s = zsum[e];
        s += __shfl_xor(s, 1, 64); s += __shfl_xor(s, 2, 64);
        s += __shfl_xor(s, 4, 64); s += __shfl_xor(s, 8, 64);
        if (lane15 == 0) zzp[wr * 32 + (e >> 2) * 16 + lg * 4 + (e & 3)][wc] = s;
    }
    __syncthreads();
    if (t < 64) zz[n0 + t] = zzp[t][0] + zzp[t][1];
}

// Distance GEMM + sampling + outputs, 64 rows x FULL 1024 cols per block.
// A-tile (64x512 bf16 = 64KB) staged once; B streamed from L2-hot cbh. Per-bkn epilogue
// writes nd and maintains running u64 argmax keys in registers (identical winner to round 7).
// Then: cross-wave reduce (LDS overlay), counts/loss atomics, one-hot enc + qz writes.
__global__ __launch_bounds__(256) void kDSE(const ushort* __restrict__ zbh, const ushort* __restrict__ cbh,
                                            const float* __restrict__ zz, const double* __restrict__ cc,
                                            const float* __restrict__ cbf,
                                            float* __restrict__ nd, float* __restrict__ enc,
                                            float* __restrict__ qz, int* __restrict__ idx,
                                            int* __restrict__ counts, double* __restrict__ lossb,
                                            int inline_enc) {
    __shared__ __align__(16) char lds[65536];
    int t = threadIdx.x;
    int lane = t & 63, w = t >> 6;
    int lane15 = lane & 15, lg = lane >> 4;
    int bm = blockIdx.x;
    int n0 = bm * 64;
    // stage A: 16 rows per wave, 1 row (1KB) per instruction, source pre-swizzled
    #pragma unroll
    for (int i = 0; i < 16; ++i) {
        int row = w * 16 + i;
        int csrc = lane ^ (row & 7);
        async_cp16(zbh + (size_t)(n0 + row) * FD + csrc * 8, lds + row * 1024);
    }
    __syncthreads();
    float zzr[16];
    #pragma unroll
    for (int e = 0; e < 16; ++e)
        zzr[e] = zz[n0 + (e >> 2) * 16 + lg * 4 + (e & 3)];
    unsigned long long bkey[16];
    float bnd[16];
    #pragma unroll
    for (int e = 0; e < 16; ++e) { bkey[e] = 0ull; bnd[e] = 0.f; }
    bool high = n0 >= 32768;
    uint32_t csub = high ? HALFCNT : 0u;
    f32x4 zero4 = {0.f, 0.f, 0.f, 0.f};

    for (int bkn = 0; bkn < 8; ++bkn) {
        f32x4 acc[4][2];
        #pragma unroll
        for (int i = 0; i < 4; ++i) { acc[i][0] = zero4; acc[i][1] = zero4; }
        #pragma unroll
        for (int ks = 0; ks < 16; ++ks) {
            int ch = ks * 4 + lg;
            sh8 ah[4], bh[2];
            #pragma unroll
            for (int i = 0; i < 4; ++i) {
                int ra = i * 16 + lane15;
                ah[i] = *(const sh8*)(lds + ra * 1024 + ((ch ^ (ra & 7)) << 4));
            }
            #pragma unroll
            for (int j = 0; j < 2; ++j) {
                int col = bkn * 128 + w * 32 + j * 16 + lane15;
                bh[j] = *(const sh8*)(cbh + (size_t)col * FD + ch * 8);
            }
            #pragma unroll
            for (int i = 0; i < 4; ++i) {
                acc[i][0] = __builtin_amdgcn_mfma_f32_16x16x32_bf16(ah[i], bh[0], acc[i][0], 0, 0, 0);
                acc[i][1] = __builtin_amdgcn_mfma_f32_16x16x32_bf16(ah[i], bh[1], acc[i][1], 0, 0, 0);
            }
        }
        int gcol0 = bkn * 128 + w * 32 + lane15;
        double ccv0 = cc[gcol0], ccv1 = cc[gcol0 + 16];
        #pragma unroll
        for (int i = 0; i < 4; ++i)
            #pragma unroll
            for (int r = 0; r < 4; ++r) {
                int e = i * 4 + r;
                int grow = n0 + i * 16 + lg * 4 + r;
                float zzf = zzr[e];
                double zv = (double)zzf;
                size_t rowoff = (size_t)grow << 10;
                #pragma unroll
                for (int j = 0; j < 2; ++j) {
                    int gcol = gcol0 + j * 16;
                    float ndf = (float)(2.0 * (double)acc[i][j][r] - zv - (j ? ccv1 : ccv0));
                    nd[rowoff + gcol] = ndf;
                    uint32_t base = (uint32_t)grow * 1024u + (uint32_t)gcol - csub;
                    uint32_t r0, r1;
                    threefry(base, base + HALFCNT, r0, r1);
                    float gv = gumbel_f32(high ? r1 : r0);
                    float s = (ndf + zzf) * 10.0f + gv;
                    uint32_t ub = __float_as_uint(s);
                    ub ^= (uint32_t)(((int32_t)ub >> 31) | 0x80000000);
                    unsigned long long key = ((unsigned long long)ub << 32) | (uint32_t)(1023 - gcol);
                    if (key > bkey[e]) { bkey[e] = key; bnd[e] = ndf; }
                }
            }
    }
    // 16-lane max reduce carrying nd
    #pragma unroll
    for (int e = 0; e < 16; ++e) {
        unsigned long long k = bkey[e];
        float nv = bnd[e];
        #pragma unroll
        for (int m = 1; m <= 8; m <<= 1) {
            unsigned long long ok = __shfl_xor(k, m, 64);
            float on = __shfl_xor(nv, m, 64);
            if (ok > k) { k = ok; nv = on; }
        }
        bkey[e] = k; bnd[e] = nv;
    }
    __syncthreads();                       // A-tile dead; overlay reduce scratch
    unsigned long long (*rk)[4] = (unsigned long long (*)[4])lds;        // [64][4]
    float (*rn)[4] = (float (*)[4])(lds + 2048);                          // [64][4]
    int* si = (int*)(lds + 3072);                                         // [64]
    if (lane15 == 0) {
        #pragma unroll
        for (int e = 0; e < 16; ++e) {
            int row = (e >> 2) * 16 + lg * 4 + (e & 3);
            rk[row][w] = bkey[e];
            rn[row][w] = bnd[e];
        }
    }
    __syncthreads();
    if (t < 64) {
        unsigned long long best = rk[t][0];
        float nv = rn[t][0];
        #pragma unroll
        for (int e = 1; e < 4; ++e) {
            if (rk[t][e] > best) { best = rk[t][e]; nv = rn[t][e]; }
        }
        int k = 1023 - (int)(best & 0xFFFFFFFFull);
        si[t] = k;
        idx[n0 + t] = k;
        atomicAdd(&counts[k], 1);
        double dl = -(double)nv;
        for (int off = 32; off; off >>= 1) dl += __shfl_down(dl, off, 64);
        if (t == 0) atomicAdd(&lossb[bm & 255], dl);
    }
    __syncthreads();
    if (inline_enc) {
        #pragma unroll 4
        for (int r = 0; r < 64; ++r) {
            int id = si[r];
            int base = t * 4;
            float4 v;
            v.x = (id == base)     ? 1.0f : 0.0f;
            v.y = (id == base + 1) ? 1.0f : 0.0f;
            v.z = (id == base + 2) ? 1.0f : 0.0f;
            v.w = (id == base + 3) ? 1.0f : 0.0f;
            *(float4*)&enc[(size_t)(n0 + r) * KCB + base] = v;
        }
        for (int e = t; e < 64 * 128; e += 256) {
            int r = e >> 7, s2 = e & 127;
            *(float4*)&qz[(size_t)(n0 + r) * FD + s2 * 4] =
                *(const float4*)&cbf[(size_t)si[r] * FD + s2 * 4];
        }
    }
}

// Fallback enc/qz writer (only when scratch had to live in the enc region)
__global__ __launch_bounds__(256) void k_encF(const int* __restrict__ idx, const float* __restrict__ cb,
                                              float* __restrict__ enc, float* __restrict__ qz) {
    int t = threadIdx.x;
    int n0 = blockIdx.x * 16;
    __shared__ int si[16];
    if (t < 16) si[t] = idx[n0 + t];
    __syncthreads();
    #pragma unroll
    for (int r = 0; r < 16; ++r) {
        int id = si[r];
        int base = t * 4;
        float4 v;
        v.x = (id == base)     ? 1.0f : 0.0f;
        v.y = (id == base + 1) ? 1.0f : 0.0f;
        v.z = (id == base + 2) ? 1.0f : 0.0f;
        v.w = (id == base + 3) ? 1.0f : 0.0f;
        *(float4*)&enc[(size_t)(n0 + r) * KCB + base] = v;
    }
    for (int e = t; e < 16 * 128; e += 256) {
        int r = e >> 7, s = e & 127;
        *(float4*)&qz[(size_t)(n0 + r) * FD + s * 4] =
            *(const float4*)&cb[(size_t)si[r] * FD + s * 4];
    }
}

__global__ void k_scalars(const int* __restrict__ counts, const double* __restrict__ lossb,
                          float* __restrict__ out) {
    int t = threadIdx.x;
    double s = 0.0;
    for (int k = t; k < KCB; k += 256) {
        double p = (double)counts[k] * (1.0 / 65536.0);
        s += p * log(p + 1e-10);
    }
    double lsum = lossb[t];
    for (int off = 32; off; off >>= 1) {
        s += __shfl_down(s, off, 64);
        lsum += __shfl_down(lsum, off, 64);
    }
    __shared__ double red[4], redl[4];
    int lane = t & 63, w = t >> 6;
    if (lane == 0) { red[w] = s; redl[w] = lsum; }
    __syncthreads();
    if (t == 0) {
        double tot = red[0] + red[1] + red[2] + red[3];
        double ltot = redl[0] + redl[1] + redl[2] + redl[3];
        out[OFF_PERP] = (float)exp(-tot);
        out[0] = (float)(ltot * (2.0 / 33554432.0));
    }
}

extern "C" void kernel_launch(void* const* d_in, const int* in_sizes, int n_in,
                              void* d_out, int out_size, void* d_ws, size_t ws_size,
                              hipStream_t stream) {
    const float* X  = (const float*)d_in[0];
    const float* W1 = (const float*)d_in[1];
    const float* b1 = (const float*)d_in[2];
    const float* W2 = (const float*)d_in[3];
    const float* b2 = (const float*)d_in[4];
    const float* cb = (const float*)d_in[5];

    float* out = (float*)d_out;
    float* qz  = out + (size_t)OFF_Q;
    float* enc = out + (size_t)OFF_ENC;
    float* nd  = out + (size_t)OFF_ND;

    float* zz = (float*)d_ws;            // [65536]
    double* cc = (double*)(zz + 65536);  // [1024]
    double* lossb = cc + 1024;           // [256]
    int* counts = (int*)(lossb + 256);   // [1024]
    int* idx = counts + 1024;            // [65536]

    bool big_ws = ws_size >= ((size_t)100 << 20);
    char* big = big_ws ? ((char*)d_ws + (1 << 20)) : (char*)(enc + 2);
    ushort* ub   = (ushort*)big;
    ushort* zbh  = ub;                   // [65536*512]
    ushort* cbh  = ub + 33554432;        // [1024*512]
    ushort* w1th = ub + 34078720;        // [128*1024]
    ushort* w2th = ub + 34209792;        // [512*128]

    k_prep<<<641, 256, 0, stream>>>(cb, W1, W2, cbh, cc, w1th, w2th, counts, lossb);
    kAB<<<1024, 256, 0, stream>>>(X, w1th, b1, w2th, b2, zbh, zz);
    kDSE<<<1024, 256, 0, stream>>>(zbh, cbh, zz, cc, cb, nd, enc, qz, idx, counts, lossb,
                                   big_ws ? 1 : 0);
    if (!big_ws) k_encF<<<4096, 256, 0, stream>>>(idx, cb, enc, qz);
    k_scalars<<<1, 256, 0, stream>>>(counts, lossb, out);
}

// Round 9
// 473.597 us; speedup vs baseline: 1.4030x; 1.4030x over previous
//
#include <hip/hip_runtime.h>
#include <stdint.h>

#define N_ROWS 65536
#define DIM 1024
#define HID 128
#define FD 512
#define KCB 1024
#define HALFCNT 33554432u

#define OFF_Q    1
#define OFF_PERP 33554433
#define OFF_ENC  33554434
#define OFF_ND   100663298

typedef __attribute__((ext_vector_type(8))) short sh8;     // 8 bf16 in 4 VGPRs
typedef __attribute__((ext_vector_type(4))) float f32x4;

__device__ __forceinline__ uint32_t rotl32(uint32_t v, int r) { return (v << r) | (v >> (32 - r)); }

// JAX threefry2x32 with key (0, 42)
__device__ __forceinline__ void threefry(uint32_t c0, uint32_t c1, uint32_t& o0, uint32_t& o1) {
    const uint32_t ks0 = 0u, ks1 = 42u, ks2 = 0x1BD11BDAu ^ 0u ^ 42u;
    uint32_t x0 = c0 + ks0, x1 = c1 + ks1;
#define TFR(r) x0 += x1; x1 = rotl32(x1, r); x1 ^= x0;
    TFR(13) TFR(15) TFR(26) TFR(6)  x0 += ks1; x1 += ks2 + 1u;
    TFR(17) TFR(29) TFR(16) TFR(24) x0 += ks2; x1 += ks0 + 2u;
    TFR(13) TFR(15) TFR(26) TFR(6)  x0 += ks0; x1 += ks1 + 3u;
    TFR(17) TFR(29) TFR(16) TFR(24) x0 += ks1; x1 += ks2 + 4u;
    TFR(13) TFR(15) TFR(26) TFR(6)  x0 += ks2; x1 += ks0 + 5u;
#undef TFR
    o0 = x0; o1 = x1;
}

// gumbel via hw v_log_f32 (same bits as rounds 6/7)
__device__ __forceinline__ float gumbel_f32(uint32_t b) {
    uint32_t m = b >> 9;
    float u = m ? (float)m * 1.1920928955078125e-07f : 1.17549435e-38f;
    const float LN2 = 0.6931471805599453f;
    return -LN2 * __log2f(-LN2 * __log2f(u));
}

__device__ __forceinline__ ushort bf16rne(float f) {
    uint32_t u = __float_as_uint(f);
    return (ushort)((u + 0x7FFFu + ((u >> 16) & 1u)) >> 16);
}
__device__ __forceinline__ uint32_t pack2rne(float a, float b) {
    return (uint32_t)bf16rne(a) | ((uint32_t)bf16rne(b) << 16);
}

// async global->LDS, 16B per lane
__device__ __forceinline__ void async_cp16(const void* g, void* l) {
    __builtin_amdgcn_global_load_lds(
        (const __attribute__((address_space(1))) void*)g,
        (__attribute__((address_space(3))) void*)l, 16, 0, 0);
}

// Fused prep: [0,256) codebook bf16+f64 norms; [256,384) W1T; [384,640) W2T; [640] zero.
__global__ __launch_bounds__(256) void k_prep(const float* __restrict__ cb, const float* __restrict__ W1,
                                              const float* __restrict__ W2,
                                              ushort* __restrict__ cbh, double* __restrict__ cc,
                                              ushort* __restrict__ w1th, ushort* __restrict__ w2th,
                                              int* __restrict__ counts, double* __restrict__ lossb) {
    int gb = blockIdx.x, t = threadIdx.x;
    if (gb < 256) {
        int k = gb * 4 + (t >> 6), l = t & 63;
        const float4* row = (const float4*)(cb + (size_t)k * FD);
        float4 a = row[l * 2], b = row[l * 2 + 1];
        float v[8] = {a.x, a.y, a.z, a.w, b.x, b.y, b.z, b.w};
        double s = 0.0;
        uint32_t hu[4];
        #pragma unroll
        for (int e = 0; e < 4; ++e) {
            hu[e] = pack2rne(v[2 * e], v[2 * e + 1]);
            s = fma((double)v[2 * e], (double)v[2 * e], s);
            s = fma((double)v[2 * e + 1], (double)v[2 * e + 1], s);
        }
        *(uint4*)(cbh + (size_t)k * FD + l * 8) = make_uint4(hu[0], hu[1], hu[2], hu[3]);
        for (int off = 32; off; off >>= 1) s += __shfl_down(s, off, 64);
        if (l == 0) cc[k] = s;
    } else if (gb < 384) {
        int c = gb - 256;
        #pragma unroll
        for (int u = 0; u < 4; ++u) {
            int k = t + u * 256;
            w1th[(size_t)c * DIM + k] = bf16rne(W1[(size_t)k * HID + c]);
        }
    } else if (gb < 640) {
        int c = (gb - 384) * 2 + (t >> 7);
        int tt = t & 127;
        w2th[(size_t)c * HID + tt] = bf16rne(W2[(size_t)tt * FD + c]);
    } else {
        for (int k = t; k < KCB; k += 256) counts[k] = 0;
        lossb[t] = 0.0;
    }
}

// Fused MLP, 64 rows/block (r8 version — proven fast, bit-identical zbh/zz):
// phase1 h = relu(X@W1+b1) -> bf16 LDS; phase2 z = h@W2+b2 -> zbh + zz.
__global__ __launch_bounds__(256) void kAB(const float* __restrict__ X, const ushort* __restrict__ w1th,
                                           const float* __restrict__ b1, const ushort* __restrict__ w2th,
                                           const float* __restrict__ b2,
                                           ushort* __restrict__ zbh, float* __restrict__ zz) {
    __shared__ __align__(16) char lds[24576];   // phase1: x[0,8K) | w1[8K,24K); then h[0,16K)
    __shared__ float zzp[64][2];
    int t = threadIdx.x;
    int lane = t & 63, w = t >> 6;
    int wr = w >> 1, wc = w & 1;
    int lane15 = lane & 15, lg = lane >> 4;
    int n0 = blockIdx.x * 64;
    f32x4 zero4 = {0.f, 0.f, 0.f, 0.f};
    f32x4 acc[2][4];
    #pragma unroll
    for (int i = 0; i < 2; ++i)
        #pragma unroll
        for (int j = 0; j < 4; ++j) acc[i][j] = zero4;

    int xr = t >> 2;                // row this thread converts (64 rows, 4 thr/row)
    int cq = (t & 3) * 2;           // 2 chunks of 8 floats each
    int xsw = xr & 7;

    for (int k0 = 0; k0 < DIM; k0 += 64) {
        #pragma unroll
        for (int i = 0; i < 4; ++i) {          // stage W1T tile: 128 rows x 64k bf16 = 16KB
            int rr = w * 32 + i * 8;
            int row = rr + (lane >> 3);
            int csrc = (lane & 7) ^ (row & 7);
            async_cp16(w1th + (size_t)row * DIM + k0 + csrc * 8, lds + 8192 + rr * 128);
        }
        const float* xp = X + (size_t)(n0 + xr) * DIM + k0 + cq * 8;
        #pragma unroll
        for (int c = 0; c < 2; ++c) {
            float4 a = *(const float4*)(xp + c * 8);
            float4 b = *(const float4*)(xp + c * 8 + 4);
            uint4 hv;
            hv.x = pack2rne(a.x, a.y);
            hv.y = pack2rne(a.z, a.w);
            hv.z = pack2rne(b.x, b.y);
            hv.w = pack2rne(b.z, b.w);
            *(uint4*)(lds + xr * 128 + (((cq + c) ^ xsw) << 4)) = hv;
        }
        __syncthreads();
        #pragma unroll
        for (int kh = 0; kh < 2; ++kh) {
            int ch = kh * 4 + lg;
            sh8 ah[2], bh[4];
            #pragma unroll
            for (int i = 0; i < 2; ++i) {
                int ra = wr * 32 + i * 16 + lane15;
                ah[i] = *(const sh8*)(lds + ra * 128 + ((ch ^ (ra & 7)) << 4));
            }
            #pragma unroll
            for (int j = 0; j < 4; ++j) {
                int rb = wc * 64 + j * 16 + lane15;
                bh[j] = *(const sh8*)(lds + 8192 + rb * 128 + ((ch ^ (rb & 7)) << 4));
            }
            #pragma unroll
            for (int i = 0; i < 2; ++i)
                #pragma unroll
                for (int j = 0; j < 4; ++j)
                    acc[i][j] = __builtin_amdgcn_mfma_f32_16x16x32_bf16(ah[i], bh[j], acc[i][j], 0, 0, 0);
        }
        __syncthreads();
    }
    // phase-1 epilogue: h (bf16) -> LDS [64][128], XOR-swizzled
    #pragma unroll
    for (int j = 0; j < 4; ++j) {
        int hcol = wc * 64 + j * 16 + lane15;
        float b1v = b1[hcol];
        int k8 = hcol >> 3, klo = hcol & 7;
        #pragma unroll
        for (int i = 0; i < 2; ++i)
            #pragma unroll
            for (int r = 0; r < 4; ++r) {
                int row = wr * 32 + i * 16 + lg * 4 + r;
                ushort hb = bf16rne(fmaxf(acc[i][j][r] + b1v, 0.f));
                *(ushort*)(lds + row * 256 + ((k8 ^ (row & 7)) << 4) + klo * 2) = hb;
            }
    }
    __syncthreads();
    // phase 2: z = h @ W2 + b2, 4 chunks of 128 cols; K=128
    float zsum[8];
    #pragma unroll
    for (int e = 0; e < 8; ++e) zsum[e] = 0.f;
    for (int c2 = 0; c2 < 4; ++c2) {
        f32x4 acc2[2][4];
        #pragma unroll
        for (int i = 0; i < 2; ++i)
            #pragma unroll
            for (int j = 0; j < 4; ++j) acc2[i][j] = zero4;
        #pragma unroll
        for (int kh = 0; kh < 4; ++kh) {
            int ch = kh * 4 + lg;
            sh8 ah[2], bh[4];
            #pragma unroll
            for (int i = 0; i < 2; ++i) {
                int ra = wr * 32 + i * 16 + lane15;
                ah[i] = *(const sh8*)(lds + ra * 256 + ((ch ^ (ra & 7)) << 4));
            }
            #pragma unroll
            for (int j = 0; j < 4; ++j) {
                int col = c2 * 128 + wc * 64 + j * 16 + lane15;
                bh[j] = *(const sh8*)(w2th + (size_t)col * HID + ch * 8);
            }
            #pragma unroll
            for (int i = 0; i < 2; ++i)
                #pragma unroll
                for (int j = 0; j < 4; ++j)
                    acc2[i][j] = __builtin_amdgcn_mfma_f32_16x16x32_bf16(ah[i], bh[j], acc2[i][j], 0, 0, 0);
        }
        #pragma unroll
        for (int j = 0; j < 4; ++j) {
            int col = c2 * 128 + wc * 64 + j * 16 + lane15;
            float b2v = b2[col];
            #pragma unroll
            for (int i = 0; i < 2; ++i)
                #pragma unroll
                for (int r = 0; r < 4; ++r) {
                    int row = wr * 32 + i * 16 + lg * 4 + r;
                    float v = acc2[i][j][r] + b2v;
                    zbh[(size_t)(n0 + row) * FD + col] = bf16rne(v);
                    zsum[i * 4 + r] = fmaf(v, v, zsum[i * 4 + r]);
                }
        }
    }
    #pragma unroll
    for (int e = 0; e < 8; ++e) {
        float s = zsum[e];
        s += __shfl_xor(s, 1, 64); s += __shfl_xor(s, 2, 64);
        s += __shfl_xor(s, 4, 64); s += __shfl_xor(s, 8, 64);
        if (lane15 == 0) zzp[wr * 32 + (e >> 2) * 16 + lg * 4 + (e & 3)][wc] = s;
    }
    __syncthreads();
    if (t < 64) zz[n0 + t] = zzp[t][0] + zzp[t][1];
}

// Distance GEMM + fused gumbel sampling (r7 version — proven). nd = 2*dot - zz - cc;
// per (row, bkn, wave) u64 partial argmax key written to `partials` (16/row).
__global__ __launch_bounds__(256) void k_mfma3s(const ushort* __restrict__ zbh, const ushort* __restrict__ cbh,
                                                const float* __restrict__ zz, const double* __restrict__ cc,
                                                float* __restrict__ nd,
                                                unsigned long long* __restrict__ partials) {
    __shared__ __align__(16) char lds[32768];   // Ah | Bh (16 KB each)
    int t = threadIdx.x;
    int lane = t & 63, w = t >> 6;
    int wr = w >> 1, wc = w & 1;
    int bid = blockIdx.x;
    int bm = ((bid >> 6) << 3) | (bid & 7);
    int bkn = (bid >> 3) & 7;
    const ushort* Ahg = zbh + (size_t)bm * 128 * FD;
    const ushort* Bhg = cbh + (size_t)bkn * 128 * FD;

    f32x4 zero4 = {0.f, 0.f, 0.f, 0.f};
    f32x4 acc[4][4];
    #pragma unroll
    for (int i = 0; i < 4; ++i)
        #pragma unroll
        for (int j = 0; j < 4; ++j) acc[i][j] = zero4;

    for (int k0 = 0; k0 < FD; k0 += 64) {
        #pragma unroll
        for (int i = 0; i < 4; ++i) {
            int rr = w * 32 + i * 8;
            int row = rr + (lane >> 3);
            int csrc = (lane & 7) ^ (row & 7);
            size_t goff = (size_t)row * FD + k0 + csrc * 8;
            async_cp16(Ahg + goff, lds + rr * 128);
            async_cp16(Bhg + goff, lds + 16384 + rr * 128);
        }
        __syncthreads();
        #pragma unroll
        for (int kh = 0; kh < 2; ++kh) {
            int ch = kh * 4 + (lane >> 4);
            sh8 ah[4], bh[4];
            #pragma unroll
            for (int i = 0; i < 4; ++i) {
                int ra = wr * 64 + i * 16 + (lane & 15);
                ah[i] = *(const sh8*)(lds + ra * 128 + ((ch ^ (ra & 7)) << 4));
            }
            #pragma unroll
            for (int j = 0; j < 4; ++j) {
                int rb = wc * 64 + j * 16 + (lane & 15);
                bh[j] = *(const sh8*)(lds + 16384 + rb * 128 + ((ch ^ (rb & 7)) << 4));
            }
            #pragma unroll
            for (int i = 0; i < 4; ++i)
                #pragma unroll
                for (int j = 0; j < 4; ++j)
                    acc[i][j] = __builtin_amdgcn_mfma_f32_16x16x32_bf16(ah[i], bh[j], acc[i][j], 0, 0, 0);
        }
        __syncthreads();
    }
    int lane15 = lane & 15, lg = lane >> 4;
    int gcol[4];
    double ccv[4];
    #pragma unroll
    for (int j = 0; j < 4; ++j) {
        gcol[j] = bkn * 128 + wc * 64 + j * 16 + lane15;
        ccv[j] = cc[gcol[j]];
    }
    bool high = bm >= 256;                 // wave-uniform: rows >= 32768 use out1
    uint32_t csub = high ? HALFCNT : 0u;
    #pragma unroll
    for (int i = 0; i < 4; ++i)
        #pragma unroll
        for (int r = 0; r < 4; ++r) {
            int grow = bm * 128 + wr * 64 + i * 16 + lg * 4 + r;
            float zzf = zz[grow];
            double zv = (double)zzf;
            size_t rowoff = (size_t)grow << 10;
            unsigned long long bkey = 0ull;
            #pragma unroll
            for (int j = 0; j < 4; ++j) {
                float ndf = (float)(2.0 * (double)acc[i][j][r] - zv - ccv[j]);
                nd[rowoff + gcol[j]] = ndf;
                uint32_t iflat = (uint32_t)grow * 1024u + (uint32_t)gcol[j];
                uint32_t base = iflat - csub;
                uint32_t r0, r1;
                threefry(base, base + HALFCNT, r0, r1);
                float gv = gumbel_f32(high ? r1 : r0);
                float s = (ndf + zzf) * 10.0f + gv;
                uint32_t ub = __float_as_uint(s);
                ub ^= (uint32_t)(((int32_t)ub >> 31) | 0x80000000);   // monotone float->uint
                unsigned long long key = ((unsigned long long)ub << 32) | (uint32_t)(1023 - gcol[j]);
                if (key > bkey) bkey = key;
            }
            #pragma unroll
            for (int m = 1; m <= 8; m <<= 1) {
                unsigned long long o = __shfl_xor(bkey, m, 64);
                if (o > bkey) bkey = o;
            }
            if (lane15 == 0) partials[(size_t)grow * 16 + bkn * 2 + wc] = bkey;
        }
}

// Finalize: reduce 16 partials/row -> idx; counts/loss atomics (loss = -nd[n,idx]);
// write one-hot enc rows + qz = cb[idx]. 16 rows per block. (r7 version — proven.)
__global__ __launch_bounds__(256) void k_enc2(const unsigned long long* __restrict__ partials,
                                              const float* __restrict__ nd, const float* __restrict__ cb,
                                              float* __restrict__ enc, float* __restrict__ qz,
                                              int* __restrict__ counts, double* __restrict__ lossb) {
    int t = threadIdx.x;
    int n0 = blockIdx.x * 16;
    __shared__ int si[16];
    if (t < 16) {
        int n = n0 + t;
        const unsigned long long* p = partials + (size_t)n * 16;
        unsigned long long best = p[0];
        #pragma unroll
        for (int e = 1; e < 16; ++e) {
            unsigned long long v = p[e];
            if (v > best) best = v;
        }
        int k = 1023 - (int)(best & 0xFFFFFFFFull);
        si[t] = k;
        atomicAdd(&counts[k], 1);
        float ndv = nd[(size_t)n * KCB + k];
        atomicAdd(&lossb[n & 255], -(double)ndv);
    }
    __syncthreads();
    #pragma unroll
    for (int r = 0; r < 16; ++r) {
        int id = si[r];
        int base = t * 4;
        float4 v;
        v.x = (id == base)     ? 1.0f : 0.0f;
        v.y = (id == base + 1) ? 1.0f : 0.0f;
        v.z = (id == base + 2) ? 1.0f : 0.0f;
        v.w = (id == base + 3) ? 1.0f : 0.0f;
        *(float4*)&enc[(size_t)(n0 + r) * KCB + base] = v;
    }
    for (int e = t; e < 16 * 128; e += 256) {
        int r = e >> 7, s = e & 127;
        *(float4*)&qz[(size_t)(n0 + r) * FD + s * 4] =
            *(const float4*)&cb[(size_t)si[r] * FD + s * 4];
    }
}

__global__ void k_scalars(const int* __restrict__ counts, const double* __restrict__ lossb,
                          float* __restrict__ out) {
    int t = threadIdx.x;
    double s = 0.0;
    for (int k = t; k < KCB; k += 256) {
        double p = (double)counts[k] * (1.0 / 65536.0);
        s += p * log(p + 1e-10);
    }
    double lsum = lossb[t];
    for (int off = 32; off; off >>= 1) {
        s += __shfl_down(s, off, 64);
        lsum += __shfl_down(lsum, off, 64);
    }
    __shared__ double red[4], redl[4];
    int lane = t & 63, w = t >> 6;
    if (lane == 0) { red[w] = s; redl[w] = lsum; }
    __syncthreads();
    if (t == 0) {
        double tot = red[0] + red[1] + red[2] + red[3];
        double ltot = redl[0] + redl[1] + redl[2] + redl[3];
        out[OFF_PERP] = (float)exp(-tot);
        out[0] = (float)(ltot * (2.0 / 33554432.0));
    }
}

extern "C" void kernel_launch(void* const* d_in, const int* in_sizes, int n_in,
                              void* d_out, int out_size, void* d_ws, size_t ws_size,
                              hipStream_t stream) {
    const float* X  = (const float*)d_in[0];
    const float* W1 = (const float*)d_in[1];
    const float* b1 = (const float*)d_in[2];
    const float* W2 = (const float*)d_in[3];
    const float* b2 = (const float*)d_in[4];
    const float* cb = (const float*)d_in[5];

    float* out = (float*)d_out;
    float* qz  = out + (size_t)OFF_Q;
    float* enc = out + (size_t)OFF_ENC;
    float* nd  = out + (size_t)OFF_ND;

    float* zz = (float*)d_ws;            // [65536]
    double* cc = (double*)(zz + 65536);  // [1024]
    double* lossb = cc + 1024;           // [256]
    int* counts = (int*)(lossb + 256);   // [1024]

    bool big_ws = ws_size >= ((size_t)100 << 20);
    char* big = big_ws ? ((char*)d_ws + (1 << 20)) : (char*)(enc + 2);
    unsigned long long* partials = (unsigned long long*)big;   // [65536*16] = 8 MB
    ushort* ub   = (ushort*)(big + ((size_t)9 << 20));
    ushort* zbh  = ub;                   // [65536*512]
    ushort* cbh  = ub + 33554432;        // [1024*512]
    ushort* w1th = ub + 34078720;        // [128*1024]
    ushort* w2th = ub + 34209792;        // [512*128]

    k_prep<<<641, 256, 0, stream>>>(cb, W1, W2, cbh, cc, w1th, w2th, counts, lossb);
    kAB<<<1024, 256, 0, stream>>>(X, w1th, b1, w2th, b2, zbh, zz);
    k_mfma3s<<<4096, 256, 0, stream>>>(zbh, cbh, zz, cc, nd, partials);
    k_enc2<<<4096, 256, 0, stream>>>(partials, nd, cb, enc, qz, counts, lossb);
    k_scalars<<<1, 256, 0, stream>>>(counts, lossb, out);
}

// Round 10
// 440.145 us; speedup vs baseline: 1.5096x; 1.0760x over previous
//
#include <hip/hip_runtime.h>
#include <stdint.h>

#define N_ROWS 65536
#define DIM 1024
#define HID 128
#define FD 512
#define KCB 1024
#define HALFCNT 33554432u

#define OFF_Q    1
#define OFF_PERP 33554433
#define OFF_ENC  33554434
#define OFF_ND   100663298

typedef __attribute__((ext_vector_type(8))) short sh8;     // 8 bf16 in 4 VGPRs
typedef __attribute__((ext_vector_type(4))) float f32x4;

__device__ __forceinline__ uint32_t rotl32(uint32_t v, int r) { return (v << r) | (v >> (32 - r)); }

// JAX threefry2x32 with key (0, 42)
__device__ __forceinline__ void threefry(uint32_t c0, uint32_t c1, uint32_t& o0, uint32_t& o1) {
    const uint32_t ks0 = 0u, ks1 = 42u, ks2 = 0x1BD11BDAu ^ 0u ^ 42u;
    uint32_t x0 = c0 + ks0, x1 = c1 + ks1;
#define TFR(r) x0 += x1; x1 = rotl32(x1, r); x1 ^= x0;
    TFR(13) TFR(15) TFR(26) TFR(6)  x0 += ks1; x1 += ks2 + 1u;
    TFR(17) TFR(29) TFR(16) TFR(24) x0 += ks2; x1 += ks0 + 2u;
    TFR(13) TFR(15) TFR(26) TFR(6)  x0 += ks0; x1 += ks1 + 3u;
    TFR(17) TFR(29) TFR(16) TFR(24) x0 += ks1; x1 += ks2 + 4u;
    TFR(13) TFR(15) TFR(26) TFR(6)  x0 += ks2; x1 += ks0 + 5u;
#undef TFR
    o0 = x0; o1 = x1;
}

// gumbel via hw v_log_f32 (same bits as rounds 6-9)
__device__ __forceinline__ float gumbel_f32(uint32_t b) {
    uint32_t m = b >> 9;
    float u = m ? (float)m * 1.1920928955078125e-07f : 1.17549435e-38f;
    const float LN2 = 0.6931471805599453f;
    return -LN2 * __log2f(-LN2 * __log2f(u));
}

__device__ __forceinline__ ushort bf16rne(float f) {
    uint32_t u = __float_as_uint(f);
    return (ushort)((u + 0x7FFFu + ((u >> 16) & 1u)) >> 16);
}
__device__ __forceinline__ uint32_t pack2rne(float a, float b) {
    return (uint32_t)bf16rne(a) | ((uint32_t)bf16rne(b) << 16);
}

// async global->LDS, 16B per lane
__device__ __forceinline__ void async_cp16(const void* g, void* l) {
    __builtin_amdgcn_global_load_lds(
        (const __attribute__((address_space(1))) void*)g,
        (__attribute__((address_space(3))) void*)l, 16, 0, 0);
}

// Fused prep: [0,256) codebook bf16+f64 norms; [256,384) W1T; [384,640) W2T; [640] zero.
__global__ __launch_bounds__(256) void k_prep(const float* __restrict__ cb, const float* __restrict__ W1,
                                              const float* __restrict__ W2,
                                              ushort* __restrict__ cbh, double* __restrict__ cc,
                                              ushort* __restrict__ w1th, ushort* __restrict__ w2th,
                                              int* __restrict__ counts, double* __restrict__ lossb) {
    int gb = blockIdx.x, t = threadIdx.x;
    if (gb < 256) {
        int k = gb * 4 + (t >> 6), l = t & 63;
        const float4* row = (const float4*)(cb + (size_t)k * FD);
        float4 a = row[l * 2], b = row[l * 2 + 1];
        float v[8] = {a.x, a.y, a.z, a.w, b.x, b.y, b.z, b.w};
        double s = 0.0;
        uint32_t hu[4];
        #pragma unroll
        for (int e = 0; e < 4; ++e) {
            hu[e] = pack2rne(v[2 * e], v[2 * e + 1]);
            s = fma((double)v[2 * e], (double)v[2 * e], s);
            s = fma((double)v[2 * e + 1], (double)v[2 * e + 1], s);
        }
        *(uint4*)(cbh + (size_t)k * FD + l * 8) = make_uint4(hu[0], hu[1], hu[2], hu[3]);
        for (int off = 32; off; off >>= 1) s += __shfl_down(s, off, 64);
        if (l == 0) cc[k] = s;
    } else if (gb < 384) {
        int c = gb - 256;
        #pragma unroll
        for (int u = 0; u < 4; ++u) {
            int k = t + u * 256;
            w1th[(size_t)c * DIM + k] = bf16rne(W1[(size_t)k * HID + c]);
        }
    } else if (gb < 640) {
        int c = (gb - 384) * 2 + (t >> 7);
        int tt = t & 127;
        w2th[(size_t)c * HID + tt] = bf16rne(W2[(size_t)tt * FD + c]);
    } else {
        for (int k = t; k < KCB; k += 256) counts[k] = 0;
        lossb[t] = 0.0;
    }
}

// Fused MLP, 64 rows/block: phase1 h = relu(X@W1+b1) -> bf16 LDS; phase2 z = h@W2+b2 -> zbh + zz.
__global__ __launch_bounds__(256) void kAB(const float* __restrict__ X, const ushort* __restrict__ w1th,
                                           const float* __restrict__ b1, const ushort* __restrict__ w2th,
                                           const float* __restrict__ b2,
                                           ushort* __restrict__ zbh, float* __restrict__ zz) {
    __shared__ __align__(16) char lds[24576];   // phase1: x[0,8K) | w1[8K,24K); then h[0,16K)
    __shared__ float zzp[64][2];
    int t = threadIdx.x;
    int lane = t & 63, w = t >> 6;
    int wr = w >> 1, wc = w & 1;
    int lane15 = lane & 15, lg = lane >> 4;
    int n0 = blockIdx.x * 64;
    f32x4 zero4 = {0.f, 0.f, 0.f, 0.f};
    f32x4 acc[2][4];
    #pragma unroll
    for (int i = 0; i < 2; ++i)
        #pragma unroll
        for (int j = 0; j < 4; ++j) acc[i][j] = zero4;

    int xr = t >> 2;                // row this thread converts (64 rows, 4 thr/row)
    int cq = (t & 3) * 2;           // 2 chunks of 8 floats each
    int xsw = xr & 7;

    for (int k0 = 0; k0 < DIM; k0 += 64) {
        #pragma unroll
        for (int i = 0; i < 4; ++i) {          // stage W1T tile: 128 rows x 64k bf16 = 16KB
            int rr = w * 32 + i * 8;
            int row = rr + (lane >> 3);
            int csrc = (lane & 7) ^ (row & 7);
            async_cp16(w1th + (size_t)row * DIM + k0 + csrc * 8, lds + 8192 + rr * 128);
        }
        const float* xp = X + (size_t)(n0 + xr) * DIM + k0 + cq * 8;
        #pragma unroll
        for (int c = 0; c < 2; ++c) {
            float4 a = *(const float4*)(xp + c * 8);
            float4 b = *(const float4*)(xp + c * 8 + 4);
            uint4 hv;
            hv.x = pack2rne(a.x, a.y);
            hv.y = pack2rne(a.z, a.w);
            hv.z = pack2rne(b.x, b.y);
            hv.w = pack2rne(b.z, b.w);
            *(uint4*)(lds + xr * 128 + (((cq + c) ^ xsw) << 4)) = hv;
        }
        __syncthreads();
        #pragma unroll
        for (int kh = 0; kh < 2; ++kh) {
            int ch = kh * 4 + lg;
            sh8 ah[2], bh[4];
            #pragma unroll
            for (int i = 0; i < 2; ++i) {
                int ra = wr * 32 + i * 16 + lane15;
                ah[i] = *(const sh8*)(lds + ra * 128 + ((ch ^ (ra & 7)) << 4));
            }
            #pragma unroll
            for (int j = 0; j < 4; ++j) {
                int rb = wc * 64 + j * 16 + lane15;
                bh[j] = *(const sh8*)(lds + 8192 + rb * 128 + ((ch ^ (rb & 7)) << 4));
            }
            #pragma unroll
            for (int i = 0; i < 2; ++i)
                #pragma unroll
                for (int j = 0; j < 4; ++j)
                    acc[i][j] = __builtin_amdgcn_mfma_f32_16x16x32_bf16(ah[i], bh[j], acc[i][j], 0, 0, 0);
        }
        __syncthreads();
    }
    // phase-1 epilogue: h (bf16) -> LDS [64][128], XOR-swizzled
    #pragma unroll
    for (int j = 0; j < 4; ++j) {
        int hcol = wc * 64 + j * 16 + lane15;
        float b1v = b1[hcol];
        int k8 = hcol >> 3, klo = hcol & 7;
        #pragma unroll
        for (int i = 0; i < 2; ++i)
            #pragma unroll
            for (int r = 0; r < 4; ++r) {
                int row = wr * 32 + i * 16 + lg * 4 + r;
                ushort hb = bf16rne(fmaxf(acc[i][j][r] + b1v, 0.f));
                *(ushort*)(lds + row * 256 + ((k8 ^ (row & 7)) << 4) + klo * 2) = hb;
            }
    }
    __syncthreads();
    // phase 2: z = h @ W2 + b2, 4 chunks of 128 cols; K=128
    float zsum[8];
    #pragma unroll
    for (int e = 0; e < 8; ++e) zsum[e] = 0.f;
    for (int c2 = 0; c2 < 4; ++c2) {
        f32x4 acc2[2][4];
        #pragma unroll
        for (int i = 0; i < 2; ++i)
            #pragma unroll
            for (int j = 0; j < 4; ++j) acc2[i][j] = zero4;
        #pragma unroll
        for (int kh = 0; kh < 4; ++kh) {
            int ch = kh * 4 + lg;
            sh8 ah[2], bh[4];
            #pragma unroll
            for (int i = 0; i < 2; ++i) {
                int ra = wr * 32 + i * 16 + lane15;
                ah[i] = *(const sh8*)(lds + ra * 256 + ((ch ^ (ra & 7)) << 4));
            }
            #pragma unroll
            for (int j = 0; j < 4; ++j) {
                int col = c2 * 128 + wc * 64 + j * 16 + lane15;
                bh[j] = *(const sh8*)(w2th + (size_t)col * HID + ch * 8);
            }
            #pragma unroll
            for (int i = 0; i < 2; ++i)
                #pragma unroll
                for (int j = 0; j < 4; ++j)
                    acc2[i][j] = __builtin_amdgcn_mfma_f32_16x16x32_bf16(ah[i], bh[j], acc2[i][j], 0, 0, 0);
        }
        #pragma unroll
        for (int j = 0; j < 4; ++j) {
            int col = c2 * 128 + wc * 64 + j * 16 + lane15;
            float b2v = b2[col];
            #pragma unroll
            for (int i = 0; i < 2; ++i)
                #pragma unroll
                for (int r = 0; r < 4; ++r) {
                    int row = wr * 32 + i * 16 + lg * 4 + r;
                    float v = acc2[i][j][r] + b2v;
                    zbh[(size_t)(n0 + row) * FD + col] = bf16rne(v);
                    zsum[i * 4 + r] = fmaf(v, v, zsum[i * 4 + r]);
                }
        }
    }
    #pragma unroll
    for (int e = 0; e < 8; ++e) {
        float s = zsum[e];
        s += __shfl_xor(s, 1, 64); s += __shfl_xor(s, 2, 64);
        s += __shfl_xor(s, 4, 64); s += __shfl_xor(s, 8, 64);
        if (lane15 == 0) zzp[wr * 32 + (e >> 2) * 16 + lg * 4 + (e & 3)][wc] = s;
    }
    __syncthreads();
    if (t < 64) zz[n0 + t] = zzp[t][0] + zzp[t][1];
}

// Distance GEMM + fused sampling, half-paired A-tile: 64 low rows [pm*64,+64) and the
// 64 paired high rows [pm*64+32768,+64) share the block (fragments i=0,1 low; i=2,3 high).
// One threefry feeds BOTH rows of a counter pair (r0->low, r1->high): 2x less RNG VALU.
// nd values / score bits / winner selection bit-identical to rounds 7/9.
__global__ __launch_bounds__(256) void k_mfma3p(const ushort* __restrict__ zbh, const ushort* __restrict__ cbh,
                                                const float* __restrict__ zz, const double* __restrict__ cc,
                                                float* __restrict__ nd,
                                                unsigned long long* __restrict__ partials) {
    __shared__ __align__(16) char lds[32768];   // Ah | Bh (16 KB each)
    int t = threadIdx.x;
    int lane = t & 63, w = t >> 6;
    int wr = w >> 1, wc = w & 1;
    int bid = blockIdx.x;
    int pm = ((bid >> 6) << 3) | (bid & 7);    // [0,512): pair-tile; 8 bkn of one pm share an XCD
    int bkn = (bid >> 3) & 7;
    const ushort* Bhg = cbh + (size_t)bkn * 128 * FD;

    f32x4 zero4 = {0.f, 0.f, 0.f, 0.f};
    f32x4 acc[4][4];
    #pragma unroll
    for (int i = 0; i < 4; ++i)
        #pragma unroll
        for (int j = 0; j < 4; ++j) acc[i][j] = zero4;

    for (int k0 = 0; k0 < FD; k0 += 64) {
        #pragma unroll
        for (int i = 0; i < 4; ++i) {
            int rr = w * 32 + i * 8;
            int row = rr + (lane >> 3);        // LDS local row 0..127
            int csrc = (lane & 7) ^ (row & 7);
            // local row -> global A row: [0,32)=lo(wr0) [32,64)=hi(wr0) [64,96)=lo(wr1) [96,128)=hi(wr1)
            int ga = pm * 64 + (row >> 6) * 32 + (row & 31) + (((row >> 5) & 1) ? 32768 : 0);
            async_cp16(zbh + (size_t)ga * FD + k0 + csrc * 8, lds + rr * 128);
            async_cp16(Bhg + (size_t)row * FD + k0 + csrc * 8, lds + 16384 + rr * 128);
        }
        __syncthreads();
        #pragma unroll
        for (int kh = 0; kh < 2; ++kh) {
            int ch = kh * 4 + (lane >> 4);
            sh8 ah[4], bh[4];
            #pragma unroll
            for (int i = 0; i < 4; ++i) {
                int ra = wr * 64 + i * 16 + (lane & 15);
                ah[i] = *(const sh8*)(lds + ra * 128 + ((ch ^ (ra & 7)) << 4));
            }
            #pragma unroll
            for (int j = 0; j < 4; ++j) {
                int rb = wc * 64 + j * 16 + (lane & 15);
                bh[j] = *(const sh8*)(lds + 16384 + rb * 128 + ((ch ^ (rb & 7)) << 4));
            }
            #pragma unroll
            for (int i = 0; i < 4; ++i)
                #pragma unroll
                for (int j = 0; j < 4; ++j)
                    acc[i][j] = __builtin_amdgcn_mfma_f32_16x16x32_bf16(ah[i], bh[j], acc[i][j], 0, 0, 0);
        }
        __syncthreads();
    }
    int lane15 = lane & 15, lg = lane >> 4;
    int gcol[4];
    double ccv[4];
    #pragma unroll
    for (int j = 0; j < 4; ++j) {
        gcol[j] = bkn * 128 + wc * 64 + j * 16 + lane15;
        ccv[j] = cc[gcol[j]];
    }
    // fragments: acc[i2] = low rows, acc[i2+2] = paired high rows (same lane/reg => same lowrow)
    #pragma unroll
    for (int i2 = 0; i2 < 2; ++i2)
        #pragma unroll
        for (int r = 0; r < 4; ++r) {
            int lowrow = pm * 64 + wr * 32 + i2 * 16 + lg * 4 + r;
            int hirow  = lowrow + 32768;
            float zlo = zz[lowrow], zhi = zz[hirow];
            double zvl = (double)zlo, zvh = (double)zhi;
            size_t rofl = (size_t)lowrow << 10;
            size_t rofh = (size_t)hirow << 10;
            unsigned long long bkl = 0ull, bkh = 0ull;
            #pragma unroll
            for (int j = 0; j < 4; ++j) {
                float ndl = (float)(2.0 * (double)acc[i2][j][r] - zvl - ccv[j]);
                float ndh = (float)(2.0 * (double)acc[i2 + 2][j][r] - zvh - ccv[j]);
                nd[rofl + gcol[j]] = ndl;
                nd[rofh + gcol[j]] = ndh;
                uint32_t base = (uint32_t)lowrow * 1024u + (uint32_t)gcol[j];
                uint32_t r0, r1;
                threefry(base, base + HALFCNT, r0, r1);
                float sl = (ndl + zlo) * 10.0f + gumbel_f32(r0);
                float sh = (ndh + zhi) * 10.0f + gumbel_f32(r1);
                uint32_t ul = __float_as_uint(sl);
                ul ^= (uint32_t)(((int32_t)ul >> 31) | 0x80000000);
                uint32_t uh = __float_as_uint(sh);
                uh ^= (uint32_t)(((int32_t)uh >> 31) | 0x80000000);
                unsigned long long kl = ((unsigned long long)ul << 32) | (uint32_t)(1023 - gcol[j]);
                unsigned long long kh2 = ((unsigned long long)uh << 32) | (uint32_t)(1023 - gcol[j]);
                if (kl > bkl) bkl = kl;
                if (kh2 > bkh) bkh = kh2;
            }
            #pragma unroll
            for (int m = 1; m <= 8; m <<= 1) {
                unsigned long long ol = __shfl_xor(bkl, m, 64);
                unsigned long long oh = __shfl_xor(bkh, m, 64);
                if (ol > bkl) bkl = ol;
                if (oh > bkh) bkh = oh;
            }
            if (lane15 == 0) {
                partials[(size_t)lowrow * 16 + bkn * 2 + wc] = bkl;
                partials[(size_t)hirow * 16 + bkn * 2 + wc] = bkh;
            }
        }
}

// Finalize: reduce 16 partials/row -> idx; counts/loss atomics (loss = -nd[n,idx]);
// write one-hot enc rows + qz = cb[idx]. 16 rows per block.
__global__ __launch_bounds__(256) void k_enc2(const unsigned long long* __restrict__ partials,
                                              const float* __restrict__ nd, const float* __restrict__ cb,
                                              float* __restrict__ enc, float* __restrict__ qz,
                                              int* __restrict__ counts, double* __restrict__ lossb) {
    int t = threadIdx.x;
    int n0 = blockIdx.x * 16;
    __shared__ int si[16];
    if (t < 16) {
        int n = n0 + t;
        const unsigned long long* p = partials + (size_t)n * 16;
        unsigned long long best = p[0];
        #pragma unroll
        for (int e = 1; e < 16; ++e) {
            unsigned long long v = p[e];
            if (v > best) best = v;
        }
        int k = 1023 - (int)(best & 0xFFFFFFFFull);
        si[t] = k;
        atomicAdd(&counts[k], 1);
        float ndv = nd[(size_t)n * KCB + k];
        atomicAdd(&lossb[n & 255], -(double)ndv);
    }
    __syncthreads();
    #pragma unroll
    for (int r = 0; r < 16; ++r) {
        int id = si[r];
        int base = t * 4;
        float4 v;
        v.x = (id == base)     ? 1.0f : 0.0f;
        v.y = (id == base + 1) ? 1.0f : 0.0f;
        v.z = (id == base + 2) ? 1.0f : 0.0f;
        v.w = (id == base + 3) ? 1.0f : 0.0f;
        *(float4*)&enc[(size_t)(n0 + r) * KCB + base] = v;
    }
    for (int e = t; e < 16 * 128; e += 256) {
        int r = e >> 7, s = e & 127;
        *(float4*)&qz[(size_t)(n0 + r) * FD + s * 4] =
            *(const float4*)&cb[(size_t)si[r] * FD + s * 4];
    }
}

__global__ void k_scalars(const int* __restrict__ counts, const double* __restrict__ lossb,
                          float* __restrict__ out) {
    int t = threadIdx.x;
    double s = 0.0;
    for (int k = t; k < KCB; k += 256) {
        double p = (double)counts[k] * (1.0 / 65536.0);
        s += p * log(p + 1e-10);
    }
    double lsum = lossb[t];
    for (int off = 32; off; off >>= 1) {
        s += __shfl_down(s, off, 64);
        lsum += __shfl_down(lsum, off, 64);
    }
    __shared__ double red[4], redl[4];
    int lane = t & 63, w = t >> 6;
    if (lane == 0) { red[w] = s; redl[w] = lsum; }
    __syncthreads();
    if (t == 0) {
        double tot = red[0] + red[1] + red[2] + red[3];
        double ltot = redl[0] + redl[1] + redl[2] + redl[3];
        out[OFF_PERP] = (float)exp(-tot);
        out[0] = (float)(ltot * (2.0 / 33554432.0));
    }
}

extern "C" void kernel_launch(void* const* d_in, const int* in_sizes, int n_in,
                              void* d_out, int out_size, void* d_ws, size_t ws_size,
                              hipStream_t stream) {
    const float* X  = (const float*)d_in[0];
    const float* W1 = (const float*)d_in[1];
    const float* b1 = (const float*)d_in[2];
    const float* W2 = (const float*)d_in[3];
    const float* b2 = (const float*)d_in[4];
    const float* cb = (const float*)d_in[5];

    float* out = (float*)d_out;
    float* qz  = out + (size_t)OFF_Q;
    float* enc = out + (size_t)OFF_ENC;
    float* nd  = out + (size_t)OFF_ND;

    float* zz = (float*)d_ws;            // [65536]
    double* cc = (double*)(zz + 65536);  // [1024]
    double* lossb = cc + 1024;           // [256]
    int* counts = (int*)(lossb + 256);   // [1024]

    bool big_ws = ws_size >= ((size_t)100 << 20);
    char* big = big_ws ? ((char*)d_ws + (1 << 20)) : (char*)(enc + 2);
    unsigned long long* partials = (unsigned long long*)big;   // [65536*16] = 8 MB
    ushort* ub   = (ushort*)(big + ((size_t)9 << 20));
    ushort* zbh  = ub;                   // [65536*512]
    ushort* cbh  = ub + 33554432;        // [1024*512]
    ushort* w1th = ub + 34078720;        // [128*1024]
    ushort* w2th = ub + 34209792;        // [512*128]

    k_prep<<<641, 256, 0, stream>>>(cb, W1, W2, cbh, cc, w1th, w2th, counts, lossb);
    kAB<<<1024, 256, 0, stream>>>(X, w1th, b1, w2th, b2, zbh, zz);
    k_mfma3p<<<4096, 256, 0, stream>>>(zbh, cbh, zz, cc, nd, partials);
    k_enc2<<<4096, 256, 0, stream>>>(partials, nd, cb, enc, qz, counts, lossb);
    k_scalars<<<1, 256, 0, stream>>>(counts, lossb, out);
}

// Round 11
// 436.317 us; speedup vs baseline: 1.5229x; 1.0088x over previous
//
#include <hip/hip_runtime.h>
#include <stdint.h>

#define N_ROWS 65536
#define DIM 1024
#define HID 128
#define FD 512
#define KCB 1024
#define HALFCNT 33554432u

#define OFF_Q    1
#define OFF_PERP 33554433
#define OFF_ENC  33554434
#define OFF_ND   100663298

typedef __attribute__((ext_vector_type(8))) short sh8;     // 8 bf16 in 4 VGPRs
typedef __attribute__((ext_vector_type(4))) float f32x4;

__device__ __forceinline__ uint32_t rotl32(uint32_t v, int r) { return (v << r) | (v >> (32 - r)); }

// JAX threefry2x32 with key (0, 42)
__device__ __forceinline__ void threefry(uint32_t c0, uint32_t c1, uint32_t& o0, uint32_t& o1) {
    const uint32_t ks0 = 0u, ks1 = 42u, ks2 = 0x1BD11BDAu ^ 0u ^ 42u;
    uint32_t x0 = c0 + ks0, x1 = c1 + ks1;
#define TFR(r) x0 += x1; x1 = rotl32(x1, r); x1 ^= x0;
    TFR(13) TFR(15) TFR(26) TFR(6)  x0 += ks1; x1 += ks2 + 1u;
    TFR(17) TFR(29) TFR(16) TFR(24) x0 += ks2; x1 += ks0 + 2u;
    TFR(13) TFR(15) TFR(26) TFR(6)  x0 += ks0; x1 += ks1 + 3u;
    TFR(17) TFR(29) TFR(16) TFR(24) x0 += ks1; x1 += ks2 + 4u;
    TFR(13) TFR(15) TFR(26) TFR(6)  x0 += ks2; x1 += ks0 + 5u;
#undef TFR
    o0 = x0; o1 = x1;
}

// gumbel via hw v_log_f32 (same bits as rounds 6-10)
__device__ __forceinline__ float gumbel_f32(uint32_t b) {
    uint32_t m = b >> 9;
    float u = m ? (float)m * 1.1920928955078125e-07f : 1.17549435e-38f;
    const float LN2 = 0.6931471805599453f;
    return -LN2 * __log2f(-LN2 * __log2f(u));
}

__device__ __forceinline__ ushort bf16rne(float f) {
    uint32_t u = __float_as_uint(f);
    return (ushort)((u + 0x7FFFu + ((u >> 16) & 1u)) >> 16);
}
__device__ __forceinline__ uint32_t pack2rne(float a, float b) {
    return (uint32_t)bf16rne(a) | ((uint32_t)bf16rne(b) << 16);
}

// async global->LDS, 16B per lane
__device__ __forceinline__ void async_cp16(const void* g, void* l) {
    __builtin_amdgcn_global_load_lds(
        (const __attribute__((address_space(1))) void*)g,
        (__attribute__((address_space(3))) void*)l, 16, 0, 0);
}

__device__ __forceinline__ void nt_store4(float* p, float x, float y, float z, float w) {
    f32x4 v = {x, y, z, w};
    __builtin_nontemporal_store(v, (f32x4*)p);
}

// Fused prep: [0,256) codebook bf16+f64 norms; [256,384) W1T; [384,640) W2T;
// [640] zero counts/lossb; [641,673) zero wkey.
__global__ __launch_bounds__(256) void k_prep(const float* __restrict__ cb, const float* __restrict__ W1,
                                              const float* __restrict__ W2,
                                              ushort* __restrict__ cbh, double* __restrict__ cc,
                                              ushort* __restrict__ w1th, ushort* __restrict__ w2th,
                                              int* __restrict__ counts, double* __restrict__ lossb,
                                              unsigned long long* __restrict__ wkey) {
    int gb = blockIdx.x, t = threadIdx.x;
    if (gb < 256) {
        int k = gb * 4 + (t >> 6), l = t & 63;
        const float4* row = (const float4*)(cb + (size_t)k * FD);
        float4 a = row[l * 2], b = row[l * 2 + 1];
        float v[8] = {a.x, a.y, a.z, a.w, b.x, b.y, b.z, b.w};
        double s = 0.0;
        uint32_t hu[4];
        #pragma unroll
        for (int e = 0; e < 4; ++e) {
            hu[e] = pack2rne(v[2 * e], v[2 * e + 1]);
            s = fma((double)v[2 * e], (double)v[2 * e], s);
            s = fma((double)v[2 * e + 1], (double)v[2 * e + 1], s);
        }
        *(uint4*)(cbh + (size_t)k * FD + l * 8) = make_uint4(hu[0], hu[1], hu[2], hu[3]);
        for (int off = 32; off; off >>= 1) s += __shfl_down(s, off, 64);
        if (l == 0) cc[k] = s;
    } else if (gb < 384) {
        int c = gb - 256;
        #pragma unroll
        for (int u = 0; u < 4; ++u) {
            int k = t + u * 256;
            w1th[(size_t)c * DIM + k] = bf16rne(W1[(size_t)k * HID + c]);
        }
    } else if (gb < 640) {
        int c = (gb - 384) * 2 + (t >> 7);
        int tt = t & 127;
        w2th[(size_t)c * HID + tt] = bf16rne(W2[(size_t)tt * FD + c]);
    } else if (gb == 640) {
        for (int k = t; k < KCB; k += 256) counts[k] = 0;
        lossb[t] = 0.0;
    } else {
        unsigned long long* p = wkey + (size_t)(gb - 641) * 2048;
        #pragma unroll
        for (int u = 0; u < 8; ++u) p[t + u * 256] = 0ull;
    }
}

// Fused MLP, 64 rows/block: phase1 h = relu(X@W1+b1) -> bf16 LDS; phase2 z = h@W2+b2 -> zbh + zz.
__global__ __launch_bounds__(256) void kAB(const float* __restrict__ X, const ushort* __restrict__ w1th,
                                           const float* __restrict__ b1, const ushort* __restrict__ w2th,
                                           const float* __restrict__ b2,
                                           ushort* __restrict__ zbh, float* __restrict__ zz) {
    __shared__ __align__(16) char lds[24576];   // phase1: x[0,8K) | w1[8K,24K); then h[0,16K)
    __shared__ float zzp[64][2];
    int t = threadIdx.x;
    int lane = t & 63, w = t >> 6;
    int wr = w >> 1, wc = w & 1;
    int lane15 = lane & 15, lg = lane >> 4;
    int n0 = blockIdx.x * 64;
    f32x4 zero4 = {0.f, 0.f, 0.f, 0.f};
    f32x4 acc[2][4];
    #pragma unroll
    for (int i = 0; i < 2; ++i)
        #pragma unroll
        for (int j = 0; j < 4; ++j) acc[i][j] = zero4;

    int xr = t >> 2;
    int cq = (t & 3) * 2;
    int xsw = xr & 7;

    for (int k0 = 0; k0 < DIM; k0 += 64) {
        #pragma unroll
        for (int i = 0; i < 4; ++i) {
            int rr = w * 32 + i * 8;
            int row = rr + (lane >> 3);
            int csrc = (lane & 7) ^ (row & 7);
            async_cp16(w1th + (size_t)row * DIM + k0 + csrc * 8, lds + 8192 + rr * 128);
        }
        const float* xp = X + (size_t)(n0 + xr) * DIM + k0 + cq * 8;
        #pragma unroll
        for (int c = 0; c < 2; ++c) {
            float4 a = *(const float4*)(xp + c * 8);
            float4 b = *(const float4*)(xp + c * 8 + 4);
            uint4 hv;
            hv.x = pack2rne(a.x, a.y);
            hv.y = pack2rne(a.z, a.w);
            hv.z = pack2rne(b.x, b.y);
            hv.w = pack2rne(b.z, b.w);
            *(uint4*)(lds + xr * 128 + (((cq + c) ^ xsw) << 4)) = hv;
        }
        __syncthreads();
        #pragma unroll
        for (int kh = 0; kh < 2; ++kh) {
            int ch = kh * 4 + lg;
            sh8 ah[2], bh[4];
            #pragma unroll
            for (int i = 0; i < 2; ++i) {
                int ra = wr * 32 + i * 16 + lane15;
                ah[i] = *(const sh8*)(lds + ra * 128 + ((ch ^ (ra & 7)) << 4));
            }
            #pragma unroll
            for (int j = 0; j < 4; ++j) {
                int rb = wc * 64 + j * 16 + lane15;
                bh[j] = *(const sh8*)(lds + 8192 + rb * 128 + ((ch ^ (rb & 7)) << 4));
            }
            #pragma unroll
            for (int i = 0; i < 2; ++i)
                #pragma unroll
                for (int j = 0; j < 4; ++j)
                    acc[i][j] = __builtin_amdgcn_mfma_f32_16x16x32_bf16(ah[i], bh[j], acc[i][j], 0, 0, 0);
        }
        __syncthreads();
    }
    #pragma unroll
    for (int j = 0; j < 4; ++j) {
        int hcol = wc * 64 + j * 16 + lane15;
        float b1v = b1[hcol];
        int k8 = hcol >> 3, klo = hcol & 7;
        #pragma unroll
        for (int i = 0; i < 2; ++i)
            #pragma unroll
            for (int r = 0; r < 4; ++r) {
                int row = wr * 32 + i * 16 + lg * 4 + r;
                ushort hb = bf16rne(fmaxf(acc[i][j][r] + b1v, 0.f));
                *(ushort*)(lds + row * 256 + ((k8 ^ (row & 7)) << 4) + klo * 2) = hb;
            }
    }
    __syncthreads();
    float zsum[8];
    #pragma unroll
    for (int e = 0; e < 8; ++e) zsum[e] = 0.f;
    for (int c2 = 0; c2 < 4; ++c2) {
        f32x4 acc2[2][4];
        #pragma unroll
        for (int i = 0; i < 2; ++i)
            #pragma unroll
            for (int j = 0; j < 4; ++j) acc2[i][j] = zero4;
        #pragma unroll
        for (int kh = 0; kh < 4; ++kh) {
            int ch = kh * 4 + lg;
            sh8 ah[2], bh[4];
            #pragma unroll
            for (int i = 0; i < 2; ++i) {
                int ra = wr * 32 + i * 16 + lane15;
                ah[i] = *(const sh8*)(lds + ra * 256 + ((ch ^ (ra & 7)) << 4));
            }
            #pragma unroll
            for (int j = 0; j < 4; ++j) {
                int col = c2 * 128 + wc * 64 + j * 16 + lane15;
                bh[j] = *(const sh8*)(w2th + (size_t)col * HID + ch * 8);
            }
            #pragma unroll
            for (int i = 0; i < 2; ++i)
                #pragma unroll
                for (int j = 0; j < 4; ++j)
                    acc2[i][j] = __builtin_amdgcn_mfma_f32_16x16x32_bf16(ah[i], bh[j], acc2[i][j], 0, 0, 0);
        }
        #pragma unroll
        for (int j = 0; j < 4; ++j) {
            int col = c2 * 128 + wc * 64 + j * 16 + lane15;
            float b2v = b2[col];
            #pragma unroll
            for (int i = 0; i < 2; ++i)
                #pragma unroll
                for (int r = 0; r < 4; ++r) {
                    int row = wr * 32 + i * 16 + lg * 4 + r;
                    float v = acc2[i][j][r] + b2v;
                    zbh[(size_t)(n0 + row) * FD + col] = bf16rne(v);
                    zsum[i * 4 + r] = fmaf(v, v, zsum[i * 4 + r]);
                }
        }
    }
    #pragma unroll
    for (int e = 0; e < 8; ++e) {
        float s = zsum[e];
        s += __shfl_xor(s, 1, 64); s += __shfl_xor(s, 2, 64);
        s += __shfl_xor(s, 4, 64); s += __shfl_xor(s, 8, 64);
        if (lane15 == 0) zzp[wr * 32 + (e >> 2) * 16 + lg * 4 + (e & 3)][wc] = s;
    }
    __syncthreads();
    if (t < 64) zz[n0 + t] = zzp[t][0] + zzp[t][1];
}

// Distance GEMM + fused sampling, half-paired A-tile (r10 structure). Winner selection via
// device-scope atomicMax on per-row u64 keys (exact max => bit-identical winner). nd nt-stored.
__global__ __launch_bounds__(256) void k_mfma3p(const ushort* __restrict__ zbh, const ushort* __restrict__ cbh,
                                                const float* __restrict__ zz, const double* __restrict__ cc,
                                                float* __restrict__ nd,
                                                unsigned long long* __restrict__ wkey) {
    __shared__ __align__(16) char lds[32768];   // Ah | Bh (16 KB each)
    int t = threadIdx.x;
    int lane = t & 63, w = t >> 6;
    int wr = w >> 1, wc = w & 1;
    int bid = blockIdx.x;
    int pm = ((bid >> 6) << 3) | (bid & 7);
    int bkn = (bid >> 3) & 7;
    const ushort* Bhg = cbh + (size_t)bkn * 128 * FD;

    f32x4 zero4 = {0.f, 0.f, 0.f, 0.f};
    f32x4 acc[4][4];
    #pragma unroll
    for (int i = 0; i < 4; ++i)
        #pragma unroll
        for (int j = 0; j < 4; ++j) acc[i][j] = zero4;

    for (int k0 = 0; k0 < FD; k0 += 64) {
        #pragma unroll
        for (int i = 0; i < 4; ++i) {
            int rr = w * 32 + i * 8;
            int row = rr + (lane >> 3);
            int csrc = (lane & 7) ^ (row & 7);
            int ga = pm * 64 + (row >> 6) * 32 + (row & 31) + (((row >> 5) & 1) ? 32768 : 0);
            async_cp16(zbh + (size_t)ga * FD + k0 + csrc * 8, lds + rr * 128);
            async_cp16(Bhg + (size_t)row * FD + k0 + csrc * 8, lds + 16384 + rr * 128);
        }
        __syncthreads();
        #pragma unroll
        for (int kh = 0; kh < 2; ++kh) {
            int ch = kh * 4 + (lane >> 4);
            sh8 ah[4], bh[4];
            #pragma unroll
            for (int i = 0; i < 4; ++i) {
                int ra = wr * 64 + i * 16 + (lane & 15);
                ah[i] = *(const sh8*)(lds + ra * 128 + ((ch ^ (ra & 7)) << 4));
            }
            #pragma unroll
            for (int j = 0; j < 4; ++j) {
                int rb = wc * 64 + j * 16 + (lane & 15);
                bh[j] = *(const sh8*)(lds + 16384 + rb * 128 + ((ch ^ (rb & 7)) << 4));
            }
            #pragma unroll
            for (int i = 0; i < 4; ++i)
                #pragma unroll
                for (int j = 0; j < 4; ++j)
                    acc[i][j] = __builtin_amdgcn_mfma_f32_16x16x32_bf16(ah[i], bh[j], acc[i][j], 0, 0, 0);
        }
        __syncthreads();
    }
    int lane15 = lane & 15, lg = lane >> 4;
    int gcol[4];
    double ccv[4];
    #pragma unroll
    for (int j = 0; j < 4; ++j) {
        gcol[j] = bkn * 128 + wc * 64 + j * 16 + lane15;
        ccv[j] = cc[gcol[j]];
    }
    #pragma unroll
    for (int i2 = 0; i2 < 2; ++i2)
        #pragma unroll
        for (int r = 0; r < 4; ++r) {
            int lowrow = pm * 64 + wr * 32 + i2 * 16 + lg * 4 + r;
            int hirow  = lowrow + 32768;
            float zlo = zz[lowrow], zhi = zz[hirow];
            double zvl = (double)zlo, zvh = (double)zhi;
            size_t rofl = (size_t)lowrow << 10;
            size_t rofh = (size_t)hirow << 10;
            unsigned long long bkl = 0ull, bkh = 0ull;
            #pragma unroll
            for (int j = 0; j < 4; ++j) {
                float ndl = (float)(2.0 * (double)acc[i2][j][r] - zvl - ccv[j]);
                float ndh = (float)(2.0 * (double)acc[i2 + 2][j][r] - zvh - ccv[j]);
                __builtin_nontemporal_store(ndl, nd + rofl + gcol[j]);
                __builtin_nontemporal_store(ndh, nd + rofh + gcol[j]);
                uint32_t base = (uint32_t)lowrow * 1024u + (uint32_t)gcol[j];
                uint32_t r0, r1;
                threefry(base, base + HALFCNT, r0, r1);
                float sl = (ndl + zlo) * 10.0f + gumbel_f32(r0);
                float sh = (ndh + zhi) * 10.0f + gumbel_f32(r1);
                uint32_t ul = __float_as_uint(sl);
                ul ^= (uint32_t)(((int32_t)ul >> 31) | 0x80000000);
                uint32_t uh = __float_as_uint(sh);
                uh ^= (uint32_t)(((int32_t)uh >> 31) | 0x80000000);
                unsigned long long kl = ((unsigned long long)ul << 32) | (uint32_t)(1023 - gcol[j]);
                unsigned long long kh2 = ((unsigned long long)uh << 32) | (uint32_t)(1023 - gcol[j]);
                if (kl > bkl) bkl = kl;
                if (kh2 > bkh) bkh = kh2;
            }
            #pragma unroll
            for (int m = 1; m <= 8; m <<= 1) {
                unsigned long long ol = __shfl_xor(bkl, m, 64);
                unsigned long long oh = __shfl_xor(bkh, m, 64);
                if (ol > bkl) bkl = ol;
                if (oh > bkh) bkh = oh;
            }
            if (lane15 == 0) {
                atomicMax(&wkey[lowrow], bkl);
                atomicMax(&wkey[hirow], bkh);
            }
        }
}

// Finalize: wkey[n] -> idx; counts/loss atomics (loss = -nd[n,idx]);
// nt-write one-hot enc rows + qz = cb[idx]. 16 rows per block.
__global__ __launch_bounds__(256) void k_enc2(const unsigned long long* __restrict__ wkey,
                                              const float* __restrict__ nd, const float* __restrict__ cb,
                                              float* __restrict__ enc, float* __restrict__ qz,
                                              int* __restrict__ counts, double* __restrict__ lossb) {
    int t = threadIdx.x;
    int n0 = blockIdx.x * 16;
    __shared__ int si[16];
    if (t < 16) {
        int n = n0 + t;
        unsigned long long best = wkey[n];
        int k = 1023 - (int)(best & 0xFFFFFFFFull);
        si[t] = k;
        atomicAdd(&counts[k], 1);
        float ndv = nd[(size_t)n * KCB + k];
        atomicAdd(&lossb[n & 255], -(double)ndv);
    }
    __syncthreads();
    #pragma unroll
    for (int r = 0; r < 16; ++r) {
        int id = si[r];
        int base = t * 4;
        nt_store4(&enc[(size_t)(n0 + r) * KCB + base],
                  (id == base)     ? 1.0f : 0.0f,
                  (id == base + 1) ? 1.0f : 0.0f,
                  (id == base + 2) ? 1.0f : 0.0f,
                  (id == base + 3) ? 1.0f : 0.0f);
    }
    for (int e = t; e < 16 * 128; e += 256) {
        int r = e >> 7, s = e & 127;
        float4 v = *(const float4*)&cb[(size_t)si[r] * FD + s * 4];
        nt_store4(&qz[(size_t)(n0 + r) * FD + s * 4], v.x, v.y, v.z, v.w);
    }
}

__global__ void k_scalars(const int* __restrict__ counts, const double* __restrict__ lossb,
                          float* __restrict__ out) {
    int t = threadIdx.x;
    double s = 0.0;
    for (int k = t; k < KCB; k += 256) {
        double p = (double)counts[k] * (1.0 / 65536.0);
        s += p * log(p + 1e-10);
    }
    double lsum = lossb[t];
    for (int off = 32; off; off >>= 1) {
        s += __shfl_down(s, off, 64);
        lsum += __shfl_down(lsum, off, 64);
    }
    __shared__ double red[4], redl[4];
    int lane = t & 63, w = t >> 6;
    if (lane == 0) { red[w] = s; redl[w] = lsum; }
    __syncthreads();
    if (t == 0) {
        double tot = red[0] + red[1] + red[2] + red[3];
        double ltot = redl[0] + redl[1] + redl[2] + redl[3];
        out[OFF_PERP] = (float)exp(-tot);
        out[0] = (float)(ltot * (2.0 / 33554432.0));
    }
}

extern "C" void kernel_launch(void* const* d_in, const int* in_sizes, int n_in,
                              void* d_out, int out_size, void* d_ws, size_t ws_size,
                              hipStream_t stream) {
    const float* X  = (const float*)d_in[0];
    const float* W1 = (const float*)d_in[1];
    const float* b1 = (const float*)d_in[2];
    const float* W2 = (const float*)d_in[3];
    const float* b2 = (const float*)d_in[4];
    const float* cb = (const float*)d_in[5];

    float* out = (float*)d_out;
    float* qz  = out + (size_t)OFF_Q;
    float* enc = out + (size_t)OFF_ENC;
    float* nd  = out + (size_t)OFF_ND;

    float* zz = (float*)d_ws;                              // [65536]
    double* cc = (double*)(zz + 65536);                    // [1024]
    double* lossb = cc + 1024;                             // [256]
    int* counts = (int*)(lossb + 256);                     // [1024]
    unsigned long long* wkey = (unsigned long long*)(counts + 1024);  // [65536]

    bool big_ws = ws_size >= ((size_t)100 << 20);
    char* big = big_ws ? ((char*)d_ws + (1 << 20)) : (char*)(enc + 2);
    ushort* ub   = (ushort*)big;
    ushort* zbh  = ub;                   // [65536*512]
    ushort* cbh  = ub + 33554432;        // [1024*512]
    ushort* w1th = ub + 34078720;        // [128*1024]
    ushort* w2th = ub + 34209792;        // [512*128]

    k_prep<<<673, 256, 0, stream>>>(cb, W1, W2, cbh, cc, w1th, w2th, counts, lossb, wkey);
    kAB<<<1024, 256, 0, stream>>>(X, w1th, b1, w2th, b2, zbh, zz);
    k_mfma3p<<<4096, 256, 0, stream>>>(zbh, cbh, zz, cc, nd, wkey);
    k_enc2<<<4096, 256, 0, stream>>>(wkey, nd, cb, enc, qz, counts, lossb);
    k_scalars<<<1, 256, 0, stream>>>(counts, lossb, out);
}